// Round 5
// baseline (136.670 us; speedup 1.0000x reference)
//
#include <hip/hip_runtime.h>

#define UNITS 256
#define NB 501               // num buckets
#define NBA 502              // A-table entries per unit (need A[NB] for idx=NB-1)
#define STEPF 0.05f
#define LBF -17.0f
#define UBF 8.0f
#define RESIDUEF -17.05f     // LB - STEP
#define LOG2E 1.4426950408889634f

#define WLO 208              // hot window idx [208,432) -> x in [-6.65, 4.55)
#define WSZ 224              // P(cold) ~ 2.7e-6; hot reads A[iw], A[iw+1]
#define UPB 32               // units per block
#define PADF 225             // LDS row stride in floats (225 entries needed; odd)
#define THREADS 512          // 8 waves. ROUND-5 KEY CHANGE: occupancy has been
                             // pinned at ~16 waves/CU across rounds 0/2/3
                             // regardless of LDS -> 1024-thread workgroups
                             // appear not to co-schedule. 512-thr blocks +
                             // 28.8 KB LDS -> 4 blocks/CU, 32 waves/CU.
#define ROWS_PB 512          // grid = 8 unit-tiles * 128 row-tiles = 1024 blocks
#define CHUNKS 8             // full prefetch, pinned in VGPRs (round-4 lesson:
                             // without the pin LLVM sinks loads past the barrier)

// native vector type: works with __builtin_nontemporal_store and as a 128-bit
// "v" inline-asm operand (HIP float4 is a class type; neither works)
typedef float floatx4 __attribute__((ext_vector_type(4)));

// ---------------------------------------------------------------------------
// Kernel 1: A-table -> d_ws (256*502*4 B = 514 KB, L2/L3-resident).
//   A[u,j] = (STEP * excl_cumsum(relu(v))[j] + RESIDUE + b[u]) * LOG2E
// Interpolation identity: A[j+1]-A[j] = STEP*w[j]*LOG2E, so
//   log2e*logit = A[idx] + frac*(A[idx+1]-A[idx]),  frac = t*20 - idx.
// One f32 per bucket (was float2 (C,w)) -> LDS window halves.
// One wave per unit, 8 entries/lane (covers j up to 511 >= 501).
// ---------------------------------------------------------------------------
__global__ __launch_bounds__(256) void build_table_kernel(
    const float* __restrict__ v, const float* __restrict__ b,
    float* __restrict__ gtab) {
  const int lane = threadIdx.x & 63;
  const int wave = threadIdx.x >> 6;
  const int u = blockIdx.x * 4 + wave;
  if (u >= UNITS) return;

  const float* vu = v + u * NB;
  float pref[8];
  float run = 0.0f;
#pragma unroll
  for (int k = 0; k < 8; ++k) {
    const int j = lane * 8 + k;
    const float wv = (j < NB) ? fmaxf(vu[j], 0.0f) : 0.0f;
    pref[k] = run;  // exclusive within-lane prefix
    run += wv;
  }
  float s = run;    // inclusive wave scan of per-lane sums
#pragma unroll
  for (int d = 1; d < 64; d <<= 1) {
    const float o = __shfl_up(s, d, 64);
    if (lane >= d) s += o;
  }
  const float base = s - run;  // exclusive lane base
  const float off = RESIDUEF + b[u];
#pragma unroll
  for (int k = 0; k < 8; ++k) {
    const int j = lane * 8 + k;
    if (j < NBA) {
      gtab[u * NBA + j] = (STEPF * (base + pref[k]) + off) * LOG2E;
    }
  }
}

// ---------------------------------------------------------------------------
// Kernel 2: stream x -> out.  Per block: 32 units x 512 rows, 512 threads.
// LDS: 32 x 225 floats = 28800 B -> 4 blocks/CU by LDS AND by wave slots
// (4 * 8 waves = 32). VGPR capped at 64 via __launch_bounds__(512, 8).
// Pipeline: stage window + issue all 8 x-prefetches (pinned), one barrier,
// then pure {ds_read2_b32 -> VALU -> nt-store} with no load waits.
// Per-wave global pattern: 8 rows x 128 B contiguous segments (unchanged).
// ---------------------------------------------------------------------------
__global__ __launch_bounds__(THREADS, 8) void iso_main_kernel(
    const float* __restrict__ x, const float* __restrict__ gtab,
    float* __restrict__ out) {
  __shared__ float tab[UPB * PADF];  // 28800 B

  const int bu = blockIdx.x & 7;            // unit tile 0..7 (UPB=32)
  const int bb = blockIdx.x >> 3;           // batch tile 0..127
  const int u0 = bu * UPB;
  const int tid = threadIdx.x;

  // ---- stage hot window: 16 threads per unit, 225 floats per unit ----
  {
    const int ul = tid >> 4;                // unit 0..31
    const int jt = tid & 15;
    const float* __restrict__ src = gtab + (u0 + ul) * NBA + WLO;
    float* __restrict__ dst = tab + ul * PADF;
#pragma unroll
    for (int r = 0; r < 14; ++r) {          // 14*16 = 224 entries
      const int j = jt + r * 16;            // 16-thread groups: 64 B runs
      dst[j] = src[j];
    }
    if (jt == 0) dst[224] = src[224];       // the +1 entry for A[iw+1]
  }

  // ---- full x prefetch: 8 chunk loads, all in flight before the barrier ----
  const int rowoff = tid >> 3;              // 0..63 within chunk
  const int col4 = tid & 7;                 // float4 col within 32-unit span
  const floatx4* __restrict__ x4 = reinterpret_cast<const floatx4*>(x);
  floatx4* __restrict__ o4 = reinterpret_cast<floatx4*>(out);
  const int g0 = (bb * ROWS_PB + rowoff) * (UNITS / 4) + bu * (UPB / 4) + col4;
  const int gstep = 64 * (UNITS / 4);       // 64 rows per chunk
  const int qrow = col4 * 4;                // first of this thread's 4 units

  floatx4 xv[CHUNKS];
#pragma unroll
  for (int c = 0; c < CHUNKS; ++c) xv[c] = x4[g0 + c * gstep];
  // Pin: force loads to complete into VGPRs here; stops LLVM from sinking
  // them past the barrier back into the loop (round-3 bug, VGPR_Count=32).
#pragma unroll
  for (int c = 0; c < CHUNKS; ++c) asm volatile("" : "+v"(xv[c]));

  __syncthreads();  // only barrier; drains staging + prefetch once

  // ---- compute loop: no load waits, stores free-run behind ----
#pragma unroll
  for (int c = 0; c < CHUNKS; ++c) {
    const floatx4 cur = xv[c];
    const float xs[4] = {cur.x, cur.y, cur.z, cur.w};
    float os[4];
#pragma unroll
    for (int k = 0; k < 4; ++k) {
      const float xc = fminf(fmaxf(xs[k], LBF + 1e-9f), UBF - 1e-9f);
      const float t = xc - LBF + STEPF;     // xc + 17.05, in (0.05, 25.05)
      const float ft = t * 20.0f;           // 1/STEP == 20
      const int idx = (int)ft;              // bucket, 1..500
      const float f = ft - (float)idx;      // frac in [0,1)
      const unsigned iw = (unsigned)(idx - WLO);
      float a0, a1;
      if (iw < WSZ) {                       // hot: one ds_read2_b32
        const float* p = &tab[qrow * PADF + k * PADF + (int)iw];
        a0 = p[0];
        a1 = p[1];
      } else {                              // ~2.7e-6 of elements: L2 hit
        const int ci = idx < 1 ? 1 : (idx > NB - 1 ? NB - 1 : idx);
        const float* g = gtab + (u0 + qrow + k) * NBA + ci;
        a0 = g[0];
        a1 = g[1];
      }
      const float l2 = fmaf(f, a1 - a0, a0);  // log2e * logit
      const float e = __builtin_amdgcn_exp2f(-l2);
      os[k] = __builtin_amdgcn_rcpf(1.0f + e);
    }
    // write-once output: nt store keeps 64 MB stream out of L2/L3
    floatx4 ov;
    ov.x = os[0]; ov.y = os[1]; ov.z = os[2]; ov.w = os[3];
    __builtin_nontemporal_store(ov, &o4[g0 + c * gstep]);
  }
}

extern "C" void kernel_launch(void* const* d_in, const int* in_sizes, int n_in,
                              void* d_out, int out_size, void* d_ws,
                              size_t ws_size, hipStream_t stream) {
  const float* x = (const float*)d_in[0];   // (65536, 256)
  const float* v = (const float*)d_in[1];   // (256, 501)
  const float* b = (const float*)d_in[2];   // (256,)
  float* out = (float*)d_out;               // (65536, 256)
  float* gtab = (float*)d_ws;               // 256*502*4 B = 514 KB

  build_table_kernel<<<64, 256, 0, stream>>>(v, b, gtab);

  const int rows = out_size / UNITS;                  // 65536
  const int grid = (UNITS / UPB) * (rows / ROWS_PB);  // 8 * 128 = 1024
  iso_main_kernel<<<grid, THREADS, 0, stream>>>(x, gtab, out);
}

// Round 6
// 131.713 us; speedup vs baseline: 1.0376x; 1.0376x over previous
//
#include <hip/hip_runtime.h>

#define UNITS 256
#define NB 501               // num buckets
#define NBA 502              // A-table entries per unit (need A[501] for idx=500)
#define STEPF 0.05f
#define LBF -17.0f
#define UBF 8.0f
#define RESIDUEF -17.05f     // LB - STEP
#define LOG2E 1.4426950408889634f

#define WLO 208              // hot window idx [208,432) -> x in [-6.65, 4.55)
#define WSZ 224              // P(cold) ~ 2.7e-6 -> ~45 elements take global path
#define UPB 32               // units per block; LDS = 32*225*4 = 28800 B
#define PADF 225             // LDS row stride in floats (odd -> bank stagger)
#define THREADS 1024         // 16 waves/CU = the empirical residency budget
#define ROWS_PB 2048         // grid = 8 unit-tiles * 32 row-tiles = 256 = 1/CU
#define CHUNKS 16            // 16 chunks of 128 rows
#define RD 3                 // ring prefetch distance (4 slots)

// native vector type: works with __builtin_nontemporal_store (HIP float4 is a
// class type and is rejected)
typedef float floatx4 __attribute__((ext_vector_type(4)));

// ---------------------------------------------------------------------------
// Kernel 1: A-table -> d_ws (256*502*4 B = 514 KB, L2/L3-resident).
//   A[u,j] = (STEP * excl_cumsum(relu(v))[j] + RESIDUE + b[u]) * LOG2E
// Interp identity: A[j+1]-A[j] = STEP*w[j]*LOG2E, so
//   log2e*logit = A[idx] + frac*(A[idx+1]-A[idx]),  frac = t*20 - idx.
// One wave per unit, 8 entries/lane (covers j through 511 >= 501).
// ---------------------------------------------------------------------------
__global__ __launch_bounds__(256) void build_table_kernel(
    const float* __restrict__ v, const float* __restrict__ b,
    float* __restrict__ gtab) {
  const int lane = threadIdx.x & 63;
  const int wave = threadIdx.x >> 6;
  const int u = blockIdx.x * 4 + wave;
  if (u >= UNITS) return;

  const float* vu = v + u * NB;
  float pref[8];
  float run = 0.0f;
#pragma unroll
  for (int k = 0; k < 8; ++k) {
    const int j = lane * 8 + k;
    const float wv = (j < NB) ? fmaxf(vu[j], 0.0f) : 0.0f;
    pref[k] = run;  // exclusive within-lane prefix
    run += wv;
  }
  float s = run;    // inclusive wave scan of per-lane sums
#pragma unroll
  for (int d = 1; d < 64; d <<= 1) {
    const float o = __shfl_up(s, d, 64);
    if (lane >= d) s += o;
  }
  const float base = s - run;  // exclusive lane base
  const float off = RESIDUEF + b[u];
#pragma unroll
  for (int k = 0; k < 8; ++k) {
    const int j = lane * 8 + k;
    if (j < NBA) {
      gtab[u * NBA + j] = (STEPF * (base + pref[k]) + off) * LOG2E;
    }
  }
}

// ---------------------------------------------------------------------------
// Kernel 2: stream x -> out.  grid = 256 blocks (exactly 1/CU), 1024 threads,
// 32 units x 2048 rows per block, 16 chunks of 128 rows.
//
// ROUND-6: the per-round VGPR counts (24/32/32) prove LLVM has been sinking
// every ring/prefetch back to just-before-use -> depth-1 pipeline serialized
// on NT-store retirement; round 4's full-prefetch held but serialized the
// read phase against the compute/store phase. Fix: depth-3 ring fenced with
// __builtin_amdgcn_sched_barrier(0) around each {load | compute+store} pair.
// Loads are compiler-visible (precise counted vmcnt waits, ~vmcnt(6) in
// steady state -> the oldest store transitively waited on is >=3 chunks
// (~10K cyc) old, beyond NT-ack latency) but cannot be sunk across a fence.
// Reads for chunk c+3 overlap compute+store of chunk c continuously.
// ---------------------------------------------------------------------------
__global__ __launch_bounds__(THREADS, 8) void iso_main_kernel(
    const float* __restrict__ x, const float* __restrict__ gtab,
    float* __restrict__ out) {
  __shared__ float tab[UPB * PADF];  // 28800 B

  const int bu = blockIdx.x & 7;            // unit tile 0..7 (UPB=32)
  const int bb = blockIdx.x >> 3;           // batch tile 0..31
  const int u0 = bu * UPB;
  const int tid = threadIdx.x;

  // ---- stage hot window: 32 threads per unit, 225 floats per unit ----
  {
    const int ul = tid >> 5;                // unit 0..31
    const int jt = tid & 31;
    const float* __restrict__ src = gtab + (u0 + ul) * NBA + WLO;
    float* __restrict__ dst = tab + ul * PADF;
#pragma unroll
    for (int r = 0; r < 7; ++r) {           // 7*32 = 224 entries, 128 B runs
      const int j = jt + r * 32;
      dst[j] = src[j];
    }
    if (jt == 0) dst[224] = src[224];       // +1 entry for A[iw+1]
  }

  // ---- addressing ----
  const int rowoff = tid >> 3;              // 0..127 within chunk
  const int col4 = tid & 7;                 // float4 col within 32-unit span
  const floatx4* __restrict__ x4 = reinterpret_cast<const floatx4*>(x);
  floatx4* __restrict__ o4 = reinterpret_cast<floatx4*>(out);
  const int g0 = (bb * ROWS_PB + rowoff) * (UNITS / 4) + bu * (UPB / 4) + col4;
  const int gstep = 128 * (UNITS / 4);      // 128 rows per chunk
  const int qrow = col4 * 4;                // first of this thread's 4 units

  __syncthreads();  // only barrier; staging drained, no x-loads in flight yet

  // ---- depth-3 fenced ring over 16 chunks ----
  floatx4 xv[4];    // fully unrolled below -> all indices compile-time consts
#pragma unroll
  for (int c = 0; c < RD; ++c) xv[c] = x4[g0 + c * gstep];
  __builtin_amdgcn_sched_barrier(0);        // prologue loads issued here

#pragma unroll
  for (int c = 0; c < CHUNKS; ++c) {
    if (c + RD < CHUNKS)
      xv[(c + RD) & 3] = x4[g0 + (c + RD) * gstep];
    __builtin_amdgcn_sched_barrier(0);      // load issued before compute

    const floatx4 cur = xv[c & 3];
    const float xs[4] = {cur.x, cur.y, cur.z, cur.w};
    float os[4];
#pragma unroll
    for (int k = 0; k < 4; ++k) {
      const float xc = fminf(fmaxf(xs[k], LBF + 1e-9f), UBF - 1e-9f);
      const float t = xc - LBF + STEPF;     // xc + 17.05, in (0.05, 25.05)
      const float ft = t * 20.0f;           // 1/STEP == 20
      const int idx = (int)ft;              // bucket, 1..500
      const float f = ft - (float)idx;      // frac in [0,1)
      const unsigned iw = (unsigned)(idx - WLO);
      float a0, a1;
      if (iw < WSZ) {                       // hot: one ds_read2_b32
        const float* p = &tab[(qrow + k) * PADF + (int)iw];
        a0 = p[0];
        a1 = p[1];
      } else {                              // ~45 elements total: L2 hit
        const int ci = idx < 1 ? 1 : (idx > NB - 1 ? NB - 1 : idx);
        const float* g = gtab + (u0 + qrow + k) * NBA + ci;
        a0 = g[0];
        a1 = g[1];
      }
      const float l2 = fmaf(f, a1 - a0, a0);  // log2e * logit
      const float e = __builtin_amdgcn_exp2f(-l2);
      os[k] = __builtin_amdgcn_rcpf(1.0f + e);
    }
    // write-once output: nt store keeps the 64 MB stream out of L2/L3
    floatx4 ov;
    ov.x = os[0]; ov.y = os[1]; ov.z = os[2]; ov.w = os[3];
    __builtin_nontemporal_store(ov, &o4[g0 + c * gstep]);
    __builtin_amdgcn_sched_barrier(0);      // store stays in its chunk
  }
}

extern "C" void kernel_launch(void* const* d_in, const int* in_sizes, int n_in,
                              void* d_out, int out_size, void* d_ws,
                              size_t ws_size, hipStream_t stream) {
  const float* x = (const float*)d_in[0];   // (65536, 256)
  const float* v = (const float*)d_in[1];   // (256, 501)
  const float* b = (const float*)d_in[2];   // (256,)
  float* out = (float*)d_out;               // (65536, 256)
  float* gtab = (float*)d_ws;               // 256*502*4 B = 514 KB

  build_table_kernel<<<64, 256, 0, stream>>>(v, b, gtab);

  const int rows = out_size / UNITS;                  // 65536
  const int grid = (UNITS / UPB) * (rows / ROWS_PB);  // 8 * 32 = 256
  iso_main_kernel<<<grid, THREADS, 0, stream>>>(x, gtab, out);
}